// Round 1
// 464.327 us; speedup vs baseline: 1.6329x; 1.6329x over previous
//
#include <hip/hip_runtime.h>
#include <hip/hip_bf16.h>
#include <stdint.h>

#define DIM 2048
#define NEXP 8
#define NTOK 8192
#define KSEL 6
#define NPAIR 28
#define SLOTS 92   // max sum of ceil(cnt_p/128) = 64 + 27, +1 safety

typedef short bf16x8 __attribute__((ext_vector_type(8)));
typedef float f32x4 __attribute__((ext_vector_type(4)));
typedef const __attribute__((address_space(1))) unsigned int GU32;
typedef __attribute__((address_space(3))) unsigned int LU32;

// pair id p <-> (a,b), a<b: p = a*(15-a)/2 + (b-a-1)
static constexpr int PA[NPAIR] = {0,0,0,0,0,0,0,1,1,1,1,1,1,2,2,2,2,2,3,3,3,3,4,4,4,5,5,6};
static constexpr int PB[NPAIR] = {1,2,3,4,5,6,7,2,3,4,5,6,7,3,4,5,6,7,4,5,6,7,5,6,7,6,7,7};

__device__ __forceinline__ unsigned short f2b(float f) {
  union { float f; uint32_t u; } v; v.f = f;
  return (unsigned short)((v.u + 0x7fffu + ((v.u >> 16) & 1u)) >> 16);
}

__global__ void zero_cnt_kernel(int* cnt) {
  if (threadIdx.x < NPAIR) cnt[threadIdx.x] = 0;
}

// One wave per token: fp32 gate scores (exact top-k w/ jax tie-break),
// write bf16 cast of x and the excluded-PAIR id. NO atomics (the old
// per-token same-line atomicAdds serialized cross-XCD and dominated runtime).
__global__ __launch_bounds__(256) void gate_kernel(
    const float* __restrict__ x, const float* __restrict__ Wg,
    const float* __restrict__ bg, unsigned short* __restrict__ xB,
    int* __restrict__ pid) {
  int t = threadIdx.x;
  int w = t >> 6, l = t & 63;
  int n = blockIdx.x * 4 + w;
  const float* xr = x + (size_t)n * DIM;
  float xv[32];
#pragma unroll
  for (int j = 0; j < 8; ++j) {
    float4 v = *(const float4*)(xr + 4 * l + 256 * j);
    xv[4 * j + 0] = v.x; xv[4 * j + 1] = v.y;
    xv[4 * j + 2] = v.z; xv[4 * j + 3] = v.w;
  }
  unsigned short* xbr = xB + (size_t)n * DIM;
#pragma unroll
  for (int j = 0; j < 8; ++j) {
    ushort4 o;
    o.x = f2b(xv[4 * j + 0]); o.y = f2b(xv[4 * j + 1]);
    o.z = f2b(xv[4 * j + 2]); o.w = f2b(xv[4 * j + 3]);
    *(ushort4*)(xbr + 4 * l + 256 * j) = o;
  }
  float sc[NEXP];
#pragma unroll
  for (int e = 0; e < NEXP; ++e) {
    const float* wr = Wg + e * DIM;
    float s = 0.f;
#pragma unroll
    for (int j = 0; j < 8; ++j) {
      float4 v = *(const float4*)(wr + 4 * l + 256 * j);
      s += xv[4 * j + 0] * v.x + xv[4 * j + 1] * v.y +
           xv[4 * j + 2] * v.z + xv[4 * j + 3] * v.w;
    }
#pragma unroll
    for (int off = 32; off > 0; off >>= 1) s += __shfl_xor(s, off, 64);
    sc[e] = s + bg[e];
  }
  if (l == 0) {
    int ex0 = -1, ex1 = -1;
#pragma unroll
    for (int e = 0; e < NEXP; ++e) {
      int rank = 0;
#pragma unroll
      for (int j = 0; j < NEXP; ++j)
        rank += (sc[j] > sc[e]) || (sc[j] == sc[e] && j < e);
      if (rank >= KSEL) { if (ex0 < 0) ex0 = e; else if (ex1 < 0) ex1 = e; }
    }
    pid[n] = ex0 * (15 - ex0) / 2 + (ex1 - ex0 - 1);
  }
}

// Two-phase bucketing: LDS histogram per block (2048 tokens), ONE global
// atomic per pair per block (4*28 = 112 total), then scatter.
__global__ __launch_bounds__(256) void bucket_kernel(
    const int* __restrict__ pid, int* __restrict__ cnt, int* __restrict__ list) {
  __shared__ int lcnt[NPAIR];
  __shared__ int gbase[NPAIR];
  int t = threadIdx.x;
  if (t < NPAIR) lcnt[t] = 0;
  __syncthreads();
  int base = blockIdx.x * 2048;
  int p[8], lp[8];
#pragma unroll
  for (int j = 0; j < 8; ++j) {
    int n = base + t + 256 * j;
    p[j] = pid[n];
    lp[j] = atomicAdd(&lcnt[p[j]], 1);
  }
  __syncthreads();
  if (t < NPAIR) gbase[t] = atomicAdd(&cnt[t], lcnt[t]);
  __syncthreads();
#pragma unroll
  for (int j = 0; j < 8; ++j) {
    int n = base + t + 256 * j;
    list[p[j] * NTOK + gbase[p[j]] + lp[j]] = n;
  }
}

// Prefix-sum of per-pair 128-row tile counts -> tile slot table.
__global__ void tilemap_kernel(const int* __restrict__ cnt, int* __restrict__ tileBase) {
  if (threadIdx.x == 0) {
    int s = 0;
    for (int p = 0; p < NPAIR; ++p) { tileBase[p] = s; s += (cnt[p] + 127) >> 7; }
    tileBase[NPAIR] = s;
  }
}

// biasPair[p][f] = sum_e be[e][f] - be[a][f] - be[b][f]
__global__ __launch_bounds__(256) void biaspair_kernel(
    const float* __restrict__ be, float* __restrict__ biasPair) {
  int f = blockIdx.x * 256 + threadIdx.x;
  float v[NEXP]; float s = 0.f;
#pragma unroll
  for (int e = 0; e < NEXP; ++e) { v[e] = be[e * DIM + f]; s += v[e]; }
#pragma unroll
  for (int pp = 0; pp < NPAIR; ++pp)
    biasPair[pp * DIM + f] = s - v[PA[pp]] - v[PB[pp]];
}

// Wpair[p] = bf16(Wsum - We[a] - We[b]) for f-rows [fbase, fbase+frows).
// Pure streaming: read We once, write 28 pair chunks.
__global__ __launch_bounds__(256) void pairw_kernel(
    const float* __restrict__ We, unsigned short* __restrict__ Wp,
    int fbase, int frows) {
  size_t pos = ((size_t)blockIdx.x * 256 + threadIdx.x) * 4;
  size_t src = (size_t)fbase * DIM + pos;
  float4 v[NEXP];
  float sx = 0.f, sy = 0.f, sz = 0.f, sw = 0.f;
#pragma unroll
  for (int e = 0; e < NEXP; ++e) {
    v[e] = *(const float4*)(We + (size_t)e * DIM * DIM + src);
    sx += v[e].x; sy += v[e].y; sz += v[e].z; sw += v[e].w;
  }
  size_t chunk = (size_t)frows * DIM;
#pragma unroll
  for (int pp = 0; pp < NPAIR; ++pp) {
    int a = PA[pp], b = PB[pp];
    ushort4 o;
    o.x = f2b(sx - v[a].x - v[b].x);
    o.y = f2b(sy - v[a].y - v[b].y);
    o.z = f2b(sz - v[a].z - v[b].z);
    o.w = f2b(sw - v[a].w - v[b].w);
    *(ushort4*)(Wp + (size_t)pp * chunk + pos) = o;
  }
}

// Pair-bucket GEMM: out[row, f0:f0+128] = gathered x rows . Wpair[p]^T + biasPair[p].
// Each out element written exactly ONCE (plain stores, bias fused, no atomics).
// 128x128 tile, BK=64, 16x16x32 bf16 MFMA, global_load_lds w=16, XOR bank swizzle.
__global__ __launch_bounds__(256, 3) void gemm_pair(
    const unsigned short* __restrict__ A, const unsigned short* __restrict__ Wp,
    const int* __restrict__ cnt, const int* __restrict__ list,
    const int* __restrict__ tileBase, const float* __restrict__ biasPair,
    float* __restrict__ out, int fbase, int frows) {
  __shared__ unsigned short sA[128 * 64];
  __shared__ unsigned short sB[128 * 64];
  __shared__ int sRows[128];
  int slot = blockIdx.y, ft = blockIdx.x;
  if (slot >= tileBase[NPAIR]) return;
  int p = 0;
  while (p + 1 < NPAIR && tileBase[p + 1] <= slot) ++p;
  int c = cnt[p];
  int m0 = (slot - tileBase[p]) * 128;

  int t = threadIdx.x;
  int w = t >> 6, l = t & 63;
  int wm = w & 1, wn = w >> 1;
  int quad = l >> 4, lr = l & 15;
  int cs = (l & 7) ^ ((l >> 3) & 7);

  if (t < 128) {
    int idx = m0 + t;
    if (idx >= c) idx = c - 1;
    sRows[t] = list[p * NTOK + idx];
  }
  __syncthreads();

  size_t rowOffA[4], rowOffB[4];
#pragma unroll
  for (int i = 0; i < 4; ++i)
    rowOffA[i] = (size_t)sRows[i * 32 + w * 8 + (l >> 3)] * DIM;
  const unsigned short* Bb =
      Wp + (size_t)p * frows * DIM + (size_t)ft * 128 * DIM;
#pragma unroll
  for (int i = 0; i < 4; ++i)
    rowOffB[i] = (size_t)(i * 32 + w * 8 + (l >> 3)) * DIM;

  f32x4 acc[4][4];
#pragma unroll
  for (int mi = 0; mi < 4; ++mi)
#pragma unroll
    for (int ni = 0; ni < 4; ++ni) {
      acc[mi][ni][0] = 0.f; acc[mi][ni][1] = 0.f;
      acc[mi][ni][2] = 0.f; acc[mi][ni][3] = 0.f;
    }

  for (int k0 = 0; k0 < DIM; k0 += 64) {
#pragma unroll
    for (int i = 0; i < 4; ++i) {
      __builtin_amdgcn_global_load_lds((GU32*)(A + rowOffA[i] + k0 + cs * 8),
          (LU32*)(sA + (i * 32 + w * 8) * 64), 16, 0, 0);
      __builtin_amdgcn_global_load_lds((GU32*)(Bb + rowOffB[i] + k0 + cs * 8),
          (LU32*)(sB + (i * 32 + w * 8) * 64), 16, 0, 0);
    }
    __syncthreads();
#pragma unroll
    for (int ks = 0; ks < 2; ++ks) {
      bf16x8 aF[4], bF[4];
#pragma unroll
      for (int mi = 0; mi < 4; ++mi)
        aF[mi] = *(const bf16x8*)(sA + (wm * 64 + mi * 16 + lr) * 64 +
                                  (((ks << 2) | quad) ^ (lr & 7)) * 8);
#pragma unroll
      for (int ni = 0; ni < 4; ++ni)
        bF[ni] = *(const bf16x8*)(sB + (wn * 64 + ni * 16 + lr) * 64 +
                                  (((ks << 2) | quad) ^ (lr & 7)) * 8);
#pragma unroll
      for (int mi = 0; mi < 4; ++mi)
#pragma unroll
        for (int ni = 0; ni < 4; ++ni)
          acc[mi][ni] = __builtin_amdgcn_mfma_f32_16x16x32_bf16(aF[mi], bF[ni], acc[mi][ni], 0, 0, 0);
    }
    __syncthreads();
  }

  int f0 = fbase + ft * 128;
  float bb[4];
#pragma unroll
  for (int ni = 0; ni < 4; ++ni)
    bb[ni] = biasPair[p * DIM + f0 + wn * 64 + ni * 16 + lr];
#pragma unroll
  for (int mi = 0; mi < 4; ++mi) {
#pragma unroll
    for (int i = 0; i < 4; ++i) {
      int lrow = wm * 64 + mi * 16 + quad * 4 + i;
      if (m0 + lrow < c) {
        float* orow = out + (size_t)sRows[lrow] * DIM + f0;
#pragma unroll
        for (int ni = 0; ni < 4; ++ni)
          orow[wn * 64 + ni * 16 + lr] = acc[mi][ni][i] + bb[ni];
      }
    }
  }
}

extern "C" void kernel_launch(void* const* d_in, const int* in_sizes, int n_in,
                              void* d_out, int out_size, void* d_ws, size_t ws_size,
                              hipStream_t stream) {
  const float* x  = (const float*)d_in[0];
  const float* Wg = (const float*)d_in[1];
  const float* bg = (const float*)d_in[2];
  const float* We = (const float*)d_in[3];
  const float* be = (const float*)d_in[4];
  float* out = (float*)d_out;

  char* ws = (char*)d_ws;
  unsigned short* xB = (unsigned short*)ws; ws += (size_t)NTOK * DIM * 2;
  int* pid = (int*)ws;          ws += (size_t)NTOK * 4;
  int* cnt = (int*)ws;          ws += 128;
  int* tileBase = (int*)ws;     ws += 128;
  int* list = (int*)ws;         ws += (size_t)NPAIR * NTOK * 4;
  float* biasPair = (float*)ws; ws += (size_t)NPAIR * DIM * 4;
  unsigned short* Wp = (unsigned short*)ws;

  // Choose f-chunking so Wpair fits the workspace: NR rounds of frows=DIM/NR.
  size_t avail = ws_size - (size_t)(ws - (char*)d_ws);
  int NR = 1;
  while (NR < 16 && (size_t)NPAIR * DIM * (size_t)(DIM / NR) * 2 > avail) NR <<= 1;
  int frows = DIM / NR;

  zero_cnt_kernel<<<1, 64, 0, stream>>>(cnt);
  gate_kernel<<<NTOK / 4, 256, 0, stream>>>(x, Wg, bg, xB, pid);
  bucket_kernel<<<4, 256, 0, stream>>>(pid, cnt, list);
  tilemap_kernel<<<1, 64, 0, stream>>>(cnt, tileBase);
  biaspair_kernel<<<DIM / 256, 256, 0, stream>>>(be, biasPair);
  for (int r = 0; r < NR; ++r) {
    int fbase = r * frows;
    pairw_kernel<<<(frows * DIM) / 1024, 256, 0, stream>>>(We, Wp, fbase, frows);
    gemm_pair<<<dim3(frows / 128, SLOTS), 256, 0, stream>>>(
        xB, Wp, cnt, list, tileBase, biasPair, out, fbase, frows);
  }
}